// Round 2
// baseline (16650.572 us; speedup 1.0000x reference)
//
#include <hip/hip_runtime.h>
#include <math.h>

// Per-sample fully-fused iterated CNN. One block per sample, 256 threads,
// 63.98 KB static LDS -> 2 blocks/CU.
#define RP32S 36          // zero-padded 32x36 state for conv1 (16B-aligned rows)
#define RP40S 44          // (-1)-padded 40x44 state for depthwise (16B-aligned rows)
#define H1_G  (31*33*2)   // h1 ic-pair plane: [31 rows][33 px][2 ic] = 2046 floats
#define H1_ROW (33*2)

struct SharedBufs {
    float rp32[32*RP32S];   //  4608 B
    float rp40[40*RP40S];   //  7040 B
    float h1[4*H1_G];       // 32736 B  [g][y][x][2] ic-pair interleaved
    float pbuf[1296];       //  5184 B  (pooled feats; reused as new-r tmp[784])
    float wker[169];        //   676 B
    float num_s[10];        //    40 B
    float w1s[200];         //   800 B
    float w2i[3200];        // 12800 B  interleaved [oc][g][k][2]
    float b1s[8];
    float b2s[16];
};                          // 63,980 B total

// ---- wave-cooperative FC: quarter-wave (16 lanes) per output, double accum.
// WT is [OUT][1344] (transposed, zero-padded) in d_ws. p is LDS pbuf[1296].
// Writes raw (pre-tanh) sums+bias to dst.
template<int OUT>
__device__ __forceinline__ void fc_wave(const float* __restrict__ WT,
                                        const float* __restrict__ bias,
                                        const float* __restrict__ p,
                                        float* __restrict__ dst, int tid)
{
    const int lane = tid & 63;
    const int wv   = tid >> 6;    // 0..3
    const int li   = lane & 15;
    const int qq   = lane >> 4;   // quarter 0..3
    float pr[81];
    #pragma unroll
    for (int m = 0; m < 81; ++m) pr[m] = p[m*16 + li];   // coalesced, 4x broadcast
    const int NB = (OUT + 15) / 16;
    #pragma unroll 1
    for (int jb = 0; jb < NB; ++jb) {
        const int j = jb*16 + wv*4 + qq;
        if (j < OUT) {
            const float* col = WT + j*1344 + li;
            double a = 0.0;
            #pragma unroll
            for (int m = 0; m < 81; ++m)
                a = fma((double)col[m*16], (double)pr[m], a);
            a += __shfl_xor(a, 1, 64);
            a += __shfl_xor(a, 2, 64);
            a += __shfl_xor(a, 4, 64);
            a += __shfl_xor(a, 8, 64);
            if (li == 0) dst[j] = (float)a + bias[j];
        }
    }
}

// fallback if ws too small for transposed weights: per-output lanes, W [1296][OUT]
template<int OUT>
__device__ __forceinline__ void fc_fb(const float* __restrict__ W,
                                      const float* __restrict__ bias,
                                      const float* __restrict__ p,
                                      float* __restrict__ dst, int tid)
{
    if (tid < OUT) {
        double a = 0.0;
        #pragma unroll 2
        for (int i0 = 0; i0 < 1296; i0 += 4) {
            float4 pv = *(const float4*)&p[i0];
            a = fma((double)pv.x, (double)W[(i0+0)*OUT+tid], a);
            a = fma((double)pv.y, (double)W[(i0+1)*OUT+tid], a);
            a = fma((double)pv.z, (double)W[(i0+2)*OUT+tid], a);
            a = fma((double)pv.w, (double)W[(i0+3)*OUT+tid], a);
        }
        dst[tid] = (float)a + bias[tid];
    }
}

__device__ __forceinline__ void trunk_pass(SharedBufs& sb, int tid)
{
    // ---- conv1 5x5 pad2 + relu -> h1 (ic-pair layout). 224 threads:
    // thread = (g=ic-pair, y, half-row). Writes float2 (both channels of pair).
    if (tid < 224) {
        const int g   = tid & 3;
        const int r   = tid >> 2;          // 0..55
        const int y   = r >> 1;            // 0..27
        const int hi  = r & 1;
        const int xh  = hi ? 14 : 0;
        const int ro  = hi ? 2  : 0;
        const int wb  = hi ? 12 : 0;
        const float bA = sb.b1s[2*g], bB = sb.b1s[2*g+1];
        float acc0[14], acc1[14];
        #pragma unroll
        for (int i = 0; i < 14; ++i) { acc0[i] = bA; acc1[i] = bB; }
        const float* w0 = &sb.w1s[(2*g)*25];
        const float* w1 = &sb.w1s[(2*g+1)*25];
        #pragma unroll
        for (int ky = 0; ky < 5; ++ky) {
            const float4* rr4 = (const float4*)&sb.rp32[(y+ky)*RP32S + wb];
            float rv[20];
            #pragma unroll
            for (int q4 = 0; q4 < 5; ++q4) {
                float4 t4 = rr4[q4];
                rv[q4*4+0]=t4.x; rv[q4*4+1]=t4.y; rv[q4*4+2]=t4.z; rv[q4*4+3]=t4.w;
            }
            #pragma unroll
            for (int kx = 0; kx < 5; ++kx) {
                const float wa = w0[ky*5+kx], wc = w1[ky*5+kx];
                #pragma unroll
                for (int xl = 0; xl < 14; ++xl) {
                    const float v = rv[xl + kx + ro];
                    acc0[xl] = fmaf(wa, v, acc0[xl]);
                    acc1[xl] = fmaf(wc, v, acc1[xl]);
                }
            }
        }
        #pragma unroll
        for (int xl = 0; xl < 14; ++xl) {
            float2 st;
            st.x = fmaxf(acc0[xl], 0.f);
            st.y = fmaxf(acc1[xl], 0.f);
            *(float2*)&sb.h1[g*H1_G + (y+2)*H1_ROW + (xh + xl + 2)*2] = st;
        }
    }
    __syncthreads();

    // ---- conv2 5x5 pad2 + relu + maxpool3 -> pbuf[1296]. 240 threads,
    // 2x3 pooled outputs each; ic-pairs read as float2 (b64, ~2-way banks = free).
    if (tid < 240) {
        const int c    = tid / 15;
        const int rem  = tid % 15;
        const int pyg  = rem / 3;
        const int pxg  = rem % 3;
        const int row0 = pyg * 6;
        const int col0 = pxg * 9;
        const float bias = sb.b2s[c];
        float acc[54];
        #pragma unroll
        for (int i = 0; i < 54; ++i) acc[i] = bias;
        #pragma unroll 1
        for (int g = 0; g < 4; ++g) {
            float2 wp[25];
            const float2* wsrc = (const float2*)&sb.w2i[((c*4+g)*25)*2];
            #pragma unroll
            for (int t = 0; t < 25; ++t) wp[t] = wsrc[t];
            #pragma unroll
            for (int yy = 0; yy < 10; ++yy) {
                int rr = row0 + yy; rr = rr > 30 ? 30 : rr;  // clamp: pyg==4 extras discarded
                const float2* hp = (const float2*)&sb.h1[g*H1_G + rr*H1_ROW + col0*2];
                float r0[13], r1[13];
                #pragma unroll
                for (int j = 0; j < 13; ++j) { float2 v = hp[j]; r0[j]=v.x; r1[j]=v.y; }
                #pragma unroll
                for (int t = 0; t < 6; ++t) {
                    const int ky = yy - t;
                    if (ky < 0 || ky > 4) continue;  // static after unroll
                    #pragma unroll
                    for (int kx = 0; kx < 5; ++kx) {
                        const float wa = wp[ky*5+kx].x, wc = wp[ky*5+kx].y;
                        #pragma unroll
                        for (int u = 0; u < 9; ++u)
                            acc[t*9+u] = fmaf(wa, r0[u+kx], fmaf(wc, r1[u+kx], acc[t*9+u]));
                    }
                }
            }
        }
        #pragma unroll
        for (int h = 0; h < 2; ++h) {
            const int py = pyg*2 + h;
            if (py < 9) {
                #pragma unroll
                for (int pxi = 0; pxi < 3; ++pxi) {
                    float m = acc[(h*3)*9 + pxi*3];
                    #pragma unroll
                    for (int dy = 0; dy < 3; ++dy)
                        #pragma unroll
                        for (int dx = 0; dx < 3; ++dx)
                            m = fmaxf(m, acc[(h*3+dy)*9 + pxi*3 + dx]);
                    sb.pbuf[c*81 + py*9 + pxg*3 + pxi] = fmaxf(m, 0.f);
                }
            }
        }
    }
    __syncthreads();
}

__device__ __forceinline__ void depthwise13(SharedBufs& sb, int tid)
{
    if (tid < 196) {
        const int y  = tid / 7;
        const int x0 = (tid % 7) * 4;
        float a0=0.f, a1=0.f, a2=0.f, a3=0.f;
        #pragma unroll 1
        for (int ky = 0; ky < 13; ++ky) {
            const float4* rr = (const float4*)&sb.rp40[(y+ky)*RP40S + x0];
            float rv[16];
            #pragma unroll
            for (int q = 0; q < 4; ++q) {
                float4 t = rr[q];
                rv[q*4+0]=t.x; rv[q*4+1]=t.y; rv[q*4+2]=t.z; rv[q*4+3]=t.w;
            }
            const float* wr = &sb.wker[ky*13];
            #pragma unroll
            for (int kx = 0; kx < 13; ++kx) {
                const float w = wr[kx];
                a0 = fmaf(w, rv[kx+0], a0);
                a1 = fmaf(w, rv[kx+1], a1);
                a2 = fmaf(w, rv[kx+2], a2);
                a3 = fmaf(w, rv[kx+3], a3);
            }
        }
        float* dp = &sb.pbuf[y*28 + x0];
        dp[0]=a0; dp[1]=a1; dp[2]=a2; dp[3]=a3;
    }
}

__device__ __forceinline__ void stage_weights(SharedBufs& sb, int tid,
                                              const float* __restrict__ w1,
                                              const float* __restrict__ w2,
                                              const float* __restrict__ b1,
                                              const float* __restrict__ b2)
{
    for (int i = tid; i < 200; i += 256) sb.w1s[i] = w1[i];
    for (int i = tid; i < 3200; i += 256) {
        int oc = i / 200, r = i % 200, ic = r / 25, k = r % 25;
        sb.w2i[((oc*4 + (ic>>1))*25 + k)*2 + (ic&1)] = w2[i];
    }
    if (tid < 8)  sb.b1s[tid] = b1[tid];
    if (tid < 16) sb.b2s[tid] = b2[tid];
}

template<bool USET>
__global__ __launch_bounds__(256, 2)
void modeld_fused(const float* __restrict__ x,
                  const float* __restrict__ n_w1, const float* __restrict__ n_b1,
                  const float* __restrict__ n_w2, const float* __restrict__ n_b2,
                  const float* __restrict__ n_wl, const float* __restrict__ n_bl,
                  const float* __restrict__ c_w1, const float* __restrict__ c_b1,
                  const float* __restrict__ c_w2, const float* __restrict__ c_b2,
                  const float* __restrict__ c_wl, const float* __restrict__ c_bl,
                  const float* __restrict__ wtc, const float* __restrict__ wtn,
                  float* __restrict__ out)
{
    __shared__ SharedBufs sb;
    const int b   = blockIdx.x;
    const int tid = threadIdx.x;

    for (int i = tid; i < 32*RP32S; i += 256) sb.rp32[i] = 0.f;
    for (int i = tid; i < 40*RP40S; i += 256) sb.rp40[i] = -1.f;
    for (int i = tid; i < 4*H1_G;   i += 256) sb.h1[i]   = 0.f;
    __syncthreads();

    float cur[4] = {0.f, 0.f, 0.f, 0.f};
    #pragma unroll
    for (int q = 0; q < 4; ++q) {
        int i = tid + q*256;
        if (i < 784) {
            float v = x[b*784 + i];
            cur[q] = v;
            int yy = i / 28, xx = i % 28;
            sb.rp32[(yy+2)*RP32S + xx + 2] = v;
            sb.rp40[(yy+6)*RP40S + xx + 6] = v;
        }
    }
    stage_weights(sb, tid, n_w1, n_w2, n_b1, n_b2);
    __syncthreads();

    // ---- n-trunk -> num[0..9] (raw, then tanh)
    trunk_pass(sb, tid);
    if (USET) fc_wave<10>(wtn, n_bl, sb.pbuf, sb.num_s, tid);
    else      fc_fb<10>(n_wl, n_bl, sb.pbuf, sb.num_s, tid);
    __syncthreads();
    if (tid < 10) sb.num_s[tid] = tanhf(sb.num_s[tid]);
    stage_weights(sb, tid, c_w1, c_w2, c_b1, c_b2);   // safe: nobody reads w1s/w2i here
    __syncthreads();

    float o[4];
    {
        const float n0 = sb.num_s[0];
        #pragma unroll
        for (int q = 0; q < 4; ++q) o[q] = n0 * cur[q];
    }

    // ---- 9 iterations
    for (int k = 1; k <= 9; ++k) {
        trunk_pass(sb, tid);
        if (USET) fc_wave<169>(wtc, c_bl, sb.pbuf, sb.wker, tid);
        else      fc_fb<169>(c_wl, c_bl, sb.pbuf, sb.wker, tid);
        __syncthreads();
        if (tid < 169) sb.wker[tid] = tanhf(sb.wker[tid]);
        __syncthreads();
        depthwise13(sb, tid);
        __syncthreads();
        const float nk = sb.num_s[k];
        #pragma unroll
        for (int q = 0; q < 4; ++q) {
            int i = tid + q*256;
            if (i < 784) {
                float v = sb.pbuf[i];
                o[q] = fmaf(nk, v, o[q]);
                int yy = i / 28, xx = i % 28;
                sb.rp32[(yy+2)*RP32S + xx + 2] = v;
                sb.rp40[(yy+6)*RP40S + xx + 6] = v;
            }
        }
        __syncthreads();
    }

    #pragma unroll
    for (int q = 0; q < 4; ++q) {
        int i = tid + q*256;
        if (i < 784) out[b*784 + i] = o[q];
    }
}

// Build WT: rows 0..168 = c_wl^T (zero-padded 1296->1344), rows 169..178 = n_wl^T.
__global__ void transpose_wl(const float* __restrict__ c_wl,
                             const float* __restrict__ n_wl,
                             float* __restrict__ wt)
{
    int idx = blockIdx.x*256 + threadIdx.x;
    const int TOT = 179*1344;
    if (idx >= TOT) return;
    int j = idx / 1344, i = idx % 1344;
    float v;
    if (j < 169) v = (i < 1296) ? c_wl[i*169 + j]      : 0.f;
    else         v = (i < 1296) ? n_wl[i*10 + (j-169)] : 0.f;
    wt[idx] = v;
}

extern "C" void kernel_launch(void* const* d_in, const int* in_sizes, int n_in,
                              void* d_out, int out_size, void* d_ws, size_t ws_size,
                              hipStream_t stream)
{
    const float* x    = (const float*)d_in[0];
    const float* n_w1 = (const float*)d_in[1];
    const float* n_b1 = (const float*)d_in[2];
    const float* n_w2 = (const float*)d_in[3];
    const float* n_b2 = (const float*)d_in[4];
    const float* n_wl = (const float*)d_in[5];
    const float* n_bl = (const float*)d_in[6];
    const float* c_w1 = (const float*)d_in[7];
    const float* c_b1 = (const float*)d_in[8];
    const float* c_w2 = (const float*)d_in[9];
    const float* c_b2 = (const float*)d_in[10];
    const float* c_wl = (const float*)d_in[11];
    const float* c_bl = (const float*)d_in[12];
    float* out = (float*)d_out;

    const int B = in_sizes[0] / 784;
    const size_t WT_BYTES = (size_t)179 * 1344 * sizeof(float);  // 962,304

    if (ws_size >= WT_BYTES) {
        float* wt = (float*)d_ws;
        hipLaunchKernelGGL(transpose_wl, dim3((179*1344 + 255)/256), dim3(256), 0, stream,
                           c_wl, n_wl, wt);
        hipLaunchKernelGGL(modeld_fused<true>, dim3(B), dim3(256), 0, stream,
                           x, n_w1, n_b1, n_w2, n_b2, n_wl, n_bl,
                           c_w1, c_b1, c_w2, c_b2, c_wl, c_bl,
                           wt, wt + 169*1344, out);
    } else {
        hipLaunchKernelGGL(modeld_fused<false>, dim3(B), dim3(256), 0, stream,
                           x, n_w1, n_b1, n_w2, n_b2, n_wl, n_bl,
                           c_w1, c_b1, c_w2, c_b2, c_wl, c_bl,
                           (const float*)nullptr, (const float*)nullptr, out);
    }
}

// Round 5
// 8174.403 us; speedup vs baseline: 2.0369x; 2.0369x over previous
//
#include <hip/hip_runtime.h>
#include <math.h>

// Per-sample fully-fused iterated CNN. One block per sample, 256 threads,
// 63.98 KB static LDS -> 2 blocks/CU.
// NUMERICS RECIPE (validated r1-r4): f64 *reductions* but f32 *storage* at
// every stage boundary (wker, num, state, feats) and f32 tanh — matching the
// np reference's f32-pipeline-with-accurate-BLAS-dots rounding. Do NOT keep
// wker/depthwise in f64 (r4: 7x worse). Do NOT cap VGPRs via launch_bounds
// min-waves (r2: 128-VGPR cap -> 57 GB scratch spill, 10x slowdown).
#define RP32S 36          // zero-padded 32x36 state for conv1 (16B-aligned rows)
#define RP40S 44          // (-1)-padded 40x44 state for depthwise (16B-aligned rows)
#define H1_G  (31*33*2)   // h1 ic-pair plane: [31 rows][33 px][2 ic] = 2046 floats
#define H1_ROW (33*2)

struct SharedBufs {
    float rp32[32*RP32S];   //  4608 B
    float rp40[40*RP40S];   //  7040 B
    float h1[4*H1_G];       // 32736 B  [g][y][x][2] ic-pair interleaved
    float pbuf[1296];       //  5184 B  (pooled feats; reused as new-r tmp[784])
    float wker[169];        //   676 B
    float num_s[10];        //    40 B
    float w1s[200];         //   800 B
    float w2i[3200];        // 12800 B  interleaved [oc][g][k][2]
    float b1s[8];
    float b2s[16];
};                          // 63,980 B total

// ---- wave-cooperative FC: quarter-wave (16 lanes) per output, double accum.
// WT is [OUT][1344] (transposed, zero-padded) in d_ws. p is LDS pbuf[1296].
// Writes raw (pre-tanh) sums+bias (f32 add, matching np) to dst.
template<int OUT>
__device__ __forceinline__ void fc_wave(const float* __restrict__ WT,
                                        const float* __restrict__ bias,
                                        const float* __restrict__ p,
                                        float* __restrict__ dst, int tid)
{
    const int lane = tid & 63;
    const int wv   = tid >> 6;    // 0..3
    const int li   = lane & 15;
    const int qq   = lane >> 4;   // quarter 0..3
    float pr[81];
    #pragma unroll
    for (int m = 0; m < 81; ++m) pr[m] = p[m*16 + li];   // coalesced, 4x broadcast
    const int NB = (OUT + 15) / 16;
    #pragma unroll 1
    for (int jb = 0; jb < NB; ++jb) {
        const int j = jb*16 + wv*4 + qq;
        if (j < OUT) {
            const float* col = WT + j*1344 + li;
            double a = 0.0;
            #pragma unroll
            for (int m = 0; m < 81; ++m)
                a = fma((double)col[m*16], (double)pr[m], a);
            a += __shfl_xor(a, 1, 64);
            a += __shfl_xor(a, 2, 64);
            a += __shfl_xor(a, 4, 64);
            a += __shfl_xor(a, 8, 64);
            if (li == 0) dst[j] = (float)a + bias[j];
        }
    }
}

// fallback if ws too small for transposed weights: per-output lanes, W [1296][OUT]
template<int OUT>
__device__ __forceinline__ void fc_fb(const float* __restrict__ W,
                                      const float* __restrict__ bias,
                                      const float* __restrict__ p,
                                      float* __restrict__ dst, int tid)
{
    if (tid < OUT) {
        double a = 0.0;
        #pragma unroll 2
        for (int i0 = 0; i0 < 1296; i0 += 4) {
            float4 pv = *(const float4*)&p[i0];
            a = fma((double)pv.x, (double)W[(i0+0)*OUT+tid], a);
            a = fma((double)pv.y, (double)W[(i0+1)*OUT+tid], a);
            a = fma((double)pv.z, (double)W[(i0+2)*OUT+tid], a);
            a = fma((double)pv.w, (double)W[(i0+3)*OUT+tid], a);
        }
        dst[tid] = (float)a + bias[tid];
    }
}

__device__ __forceinline__ void trunk_pass(SharedBufs& sb, int tid)
{
    // ---- conv1 5x5 pad2 + relu -> h1 (ic-pair layout). 224 threads:
    // thread = (g=ic-pair, y, half-row). Writes float2 (both channels of pair).
    if (tid < 224) {
        const int g   = tid & 3;
        const int r   = tid >> 2;          // 0..55
        const int y   = r >> 1;            // 0..27
        const int hi  = r & 1;
        const int xh  = hi ? 14 : 0;
        const int ro  = hi ? 2  : 0;
        const int wb  = hi ? 12 : 0;
        const float bA = sb.b1s[2*g], bB = sb.b1s[2*g+1];
        float acc0[14], acc1[14];
        #pragma unroll
        for (int i = 0; i < 14; ++i) { acc0[i] = bA; acc1[i] = bB; }
        const float* w0 = &sb.w1s[(2*g)*25];
        const float* w1 = &sb.w1s[(2*g+1)*25];
        #pragma unroll
        for (int ky = 0; ky < 5; ++ky) {
            const float4* rr4 = (const float4*)&sb.rp32[(y+ky)*RP32S + wb];
            float rv[20];
            #pragma unroll
            for (int q4 = 0; q4 < 5; ++q4) {
                float4 t4 = rr4[q4];
                rv[q4*4+0]=t4.x; rv[q4*4+1]=t4.y; rv[q4*4+2]=t4.z; rv[q4*4+3]=t4.w;
            }
            #pragma unroll
            for (int kx = 0; kx < 5; ++kx) {
                const float wa = w0[ky*5+kx], wc = w1[ky*5+kx];
                #pragma unroll
                for (int xl = 0; xl < 14; ++xl) {
                    const float v = rv[xl + kx + ro];
                    acc0[xl] = fmaf(wa, v, acc0[xl]);
                    acc1[xl] = fmaf(wc, v, acc1[xl]);
                }
            }
        }
        #pragma unroll
        for (int xl = 0; xl < 14; ++xl) {
            float2 st;
            st.x = fmaxf(acc0[xl], 0.f);
            st.y = fmaxf(acc1[xl], 0.f);
            *(float2*)&sb.h1[g*H1_G + (y+2)*H1_ROW + (xh + xl + 2)*2] = st;
        }
    }
    __syncthreads();

    // ---- conv2 5x5 pad2 + relu + maxpool3 -> pbuf[1296]. 240 threads,
    // 2x3 pooled outputs each; ic-pairs read as float2 (b64).
    if (tid < 240) {
        const int c    = tid / 15;
        const int rem  = tid % 15;
        const int pyg  = rem / 3;
        const int pxg  = rem % 3;
        const int row0 = pyg * 6;
        const int col0 = pxg * 9;
        const float bias = sb.b2s[c];
        float acc[54];
        #pragma unroll
        for (int i = 0; i < 54; ++i) acc[i] = bias;
        #pragma unroll 1
        for (int g = 0; g < 4; ++g) {
            float2 wp[25];
            const float2* wsrc = (const float2*)&sb.w2i[((c*4+g)*25)*2];
            #pragma unroll
            for (int t = 0; t < 25; ++t) wp[t] = wsrc[t];
            #pragma unroll
            for (int yy = 0; yy < 10; ++yy) {
                int rr = row0 + yy; rr = rr > 30 ? 30 : rr;  // clamp: pyg==4 extras discarded
                const float2* hp = (const float2*)&sb.h1[g*H1_G + rr*H1_ROW + col0*2];
                float r0[13], r1[13];
                #pragma unroll
                for (int j = 0; j < 13; ++j) { float2 v = hp[j]; r0[j]=v.x; r1[j]=v.y; }
                #pragma unroll
                for (int t = 0; t < 6; ++t) {
                    const int ky = yy - t;
                    if (ky < 0 || ky > 4) continue;  // static after unroll
                    #pragma unroll
                    for (int kx = 0; kx < 5; ++kx) {
                        const float wa = wp[ky*5+kx].x, wc = wp[ky*5+kx].y;
                        #pragma unroll
                        for (int u = 0; u < 9; ++u)
                            acc[t*9+u] = fmaf(wa, r0[u+kx], fmaf(wc, r1[u+kx], acc[t*9+u]));
                    }
                }
            }
        }
        #pragma unroll
        for (int h = 0; h < 2; ++h) {
            const int py = pyg*2 + h;
            if (py < 9) {
                #pragma unroll
                for (int pxi = 0; pxi < 3; ++pxi) {
                    float m = acc[(h*3)*9 + pxi*3];
                    #pragma unroll
                    for (int dy = 0; dy < 3; ++dy)
                        #pragma unroll
                        for (int dx = 0; dx < 3; ++dx)
                            m = fmaxf(m, acc[(h*3+dy)*9 + pxi*3 + dx]);
                    sb.pbuf[c*81 + py*9 + pxg*3 + pxi] = fmaxf(m, 0.f);
                }
            }
        }
    }
    __syncthreads();
}

__device__ __forceinline__ void depthwise13(SharedBufs& sb, int tid)
{
    if (tid < 196) {
        const int y  = tid / 7;
        const int x0 = (tid % 7) * 4;
        float a0=0.f, a1=0.f, a2=0.f, a3=0.f;
        #pragma unroll 1
        for (int ky = 0; ky < 13; ++ky) {
            const float4* rr = (const float4*)&sb.rp40[(y+ky)*RP40S + x0];
            float rv[16];
            #pragma unroll
            for (int q = 0; q < 4; ++q) {
                float4 t = rr[q];
                rv[q*4+0]=t.x; rv[q*4+1]=t.y; rv[q*4+2]=t.z; rv[q*4+3]=t.w;
            }
            const float* wr = &sb.wker[ky*13];
            #pragma unroll
            for (int kx = 0; kx < 13; ++kx) {
                const float w = wr[kx];
                a0 = fmaf(w, rv[kx+0], a0);
                a1 = fmaf(w, rv[kx+1], a1);
                a2 = fmaf(w, rv[kx+2], a2);
                a3 = fmaf(w, rv[kx+3], a3);
            }
        }
        float* dp = &sb.pbuf[y*28 + x0];
        dp[0]=a0; dp[1]=a1; dp[2]=a2; dp[3]=a3;
    }
}

__device__ __forceinline__ void stage_weights(SharedBufs& sb, int tid,
                                              const float* __restrict__ w1,
                                              const float* __restrict__ w2,
                                              const float* __restrict__ b1,
                                              const float* __restrict__ b2)
{
    for (int i = tid; i < 200; i += 256) sb.w1s[i] = w1[i];
    for (int i = tid; i < 3200; i += 256) {
        int oc = i / 200, r = i % 200, ic = r / 25, k = r % 25;
        sb.w2i[((oc*4 + (ic>>1))*25 + k)*2 + (ic&1)] = w2[i];
    }
    if (tid < 8)  sb.b1s[tid] = b1[tid];
    if (tid < 16) sb.b2s[tid] = b2[tid];
}

template<bool USET>
__global__ __launch_bounds__(256)
void modeld_fused(const float* __restrict__ x,
                  const float* __restrict__ n_w1, const float* __restrict__ n_b1,
                  const float* __restrict__ n_w2, const float* __restrict__ n_b2,
                  const float* __restrict__ n_wl, const float* __restrict__ n_bl,
                  const float* __restrict__ c_w1, const float* __restrict__ c_b1,
                  const float* __restrict__ c_w2, const float* __restrict__ c_b2,
                  const float* __restrict__ c_wl, const float* __restrict__ c_bl,
                  const float* __restrict__ wtc, const float* __restrict__ wtn,
                  float* __restrict__ out)
{
    __shared__ SharedBufs sb;
    const int b   = blockIdx.x;
    const int tid = threadIdx.x;

    for (int i = tid; i < 32*RP32S; i += 256) sb.rp32[i] = 0.f;
    for (int i = tid; i < 40*RP40S; i += 256) sb.rp40[i] = -1.f;
    for (int i = tid; i < 4*H1_G;   i += 256) sb.h1[i]   = 0.f;
    __syncthreads();

    float cur[4] = {0.f, 0.f, 0.f, 0.f};
    #pragma unroll
    for (int q = 0; q < 4; ++q) {
        int i = tid + q*256;
        if (i < 784) {
            float v = x[b*784 + i];
            cur[q] = v;
            int yy = i / 28, xx = i % 28;
            sb.rp32[(yy+2)*RP32S + xx + 2] = v;
            sb.rp40[(yy+6)*RP40S + xx + 6] = v;
        }
    }
    stage_weights(sb, tid, n_w1, n_w2, n_b1, n_b2);
    __syncthreads();

    // ---- n-trunk -> num[0..9] (raw, then f32 tanh)
    trunk_pass(sb, tid);
    if (USET) fc_wave<10>(wtn, n_bl, sb.pbuf, sb.num_s, tid);
    else      fc_fb<10>(n_wl, n_bl, sb.pbuf, sb.num_s, tid);
    __syncthreads();
    if (tid < 10) sb.num_s[tid] = tanhf(sb.num_s[tid]);
    stage_weights(sb, tid, c_w1, c_w2, c_b1, c_b2);   // safe: nobody reads w1s/w2i here
    __syncthreads();

    float o[4];
    {
        const float n0 = sb.num_s[0];
        #pragma unroll
        for (int q = 0; q < 4; ++q) o[q] = n0 * cur[q];
    }

    // ---- 9 iterations
    for (int k = 1; k <= 9; ++k) {
        trunk_pass(sb, tid);
        if (USET) fc_wave<169>(wtc, c_bl, sb.pbuf, sb.wker, tid);
        else      fc_fb<169>(c_wl, c_bl, sb.pbuf, sb.wker, tid);
        __syncthreads();
        if (tid < 169) sb.wker[tid] = tanhf(sb.wker[tid]);   // f32 tanh, f32 storage
        __syncthreads();
        depthwise13(sb, tid);
        __syncthreads();
        const float nk = sb.num_s[k];
        #pragma unroll
        for (int q = 0; q < 4; ++q) {
            int i = tid + q*256;
            if (i < 784) {
                float v = sb.pbuf[i];
                o[q] = fmaf(nk, v, o[q]);
                int yy = i / 28, xx = i % 28;
                sb.rp32[(yy+2)*RP32S + xx + 2] = v;
                sb.rp40[(yy+6)*RP40S + xx + 6] = v;
            }
        }
        __syncthreads();
    }

    #pragma unroll
    for (int q = 0; q < 4; ++q) {
        int i = tid + q*256;
        if (i < 784) out[b*784 + i] = o[q];
    }
}

// Build WT: rows 0..168 = c_wl^T (zero-padded 1296->1344), rows 169..178 = n_wl^T.
__global__ void transpose_wl(const float* __restrict__ c_wl,
                             const float* __restrict__ n_wl,
                             float* __restrict__ wt)
{
    int idx = blockIdx.x*256 + threadIdx.x;
    const int TOT = 179*1344;
    if (idx >= TOT) return;
    int j = idx / 1344, i = idx % 1344;
    float v;
    if (j < 169) v = (i < 1296) ? c_wl[i*169 + j]      : 0.f;
    else         v = (i < 1296) ? n_wl[i*10 + (j-169)] : 0.f;
    wt[idx] = v;
}

extern "C" void kernel_launch(void* const* d_in, const int* in_sizes, int n_in,
                              void* d_out, int out_size, void* d_ws, size_t ws_size,
                              hipStream_t stream)
{
    const float* x    = (const float*)d_in[0];
    const float* n_w1 = (const float*)d_in[1];
    const float* n_b1 = (const float*)d_in[2];
    const float* n_w2 = (const float*)d_in[3];
    const float* n_b2 = (const float*)d_in[4];
    const float* n_wl = (const float*)d_in[5];
    const float* n_bl = (const float*)d_in[6];
    const float* c_w1 = (const float*)d_in[7];
    const float* c_b1 = (const float*)d_in[8];
    const float* c_w2 = (const float*)d_in[9];
    const float* c_b2 = (const float*)d_in[10];
    const float* c_wl = (const float*)d_in[11];
    const float* c_bl = (const float*)d_in[12];
    float* out = (float*)d_out;

    const int B = in_sizes[0] / 784;
    const size_t WT_BYTES = (size_t)179 * 1344 * sizeof(float);  // 962,304

    if (ws_size >= WT_BYTES) {
        float* wt = (float*)d_ws;
        hipLaunchKernelGGL(transpose_wl, dim3((179*1344 + 255)/256), dim3(256), 0, stream,
                           c_wl, n_wl, wt);
        hipLaunchKernelGGL(modeld_fused<true>, dim3(B), dim3(256), 0, stream,
                           x, n_w1, n_b1, n_w2, n_b2, n_wl, n_bl,
                           c_w1, c_b1, c_w2, c_b2, c_wl, c_bl,
                           wt, wt + 169*1344, out);
    } else {
        hipLaunchKernelGGL(modeld_fused<false>, dim3(B), dim3(256), 0, stream,
                           x, n_w1, n_b1, n_w2, n_b2, n_wl, n_bl,
                           c_w1, c_b1, c_w2, c_b2, c_wl, c_bl,
                           (const float*)nullptr, (const float*)nullptr, out);
    }
}

// Round 6
// 3834.349 us; speedup vs baseline: 4.3425x; 2.1319x over previous
//
#include <hip/hip_runtime.h>
#include <math.h>

// Per-sample fully-fused iterated CNN. One block per sample, 256 threads,
// 63.98 KB static LDS -> 2 blocks/CU.
// NUMERICS RECIPE (validated r1-r5): f64 *dot-product reductions* with the
// fc_wave order (sequential m, 16-lane butterfly), but f32 *storage* at every
// stage boundary (wker, num, state, feats), f32 bias add, f32 tanh. This gave
// absmax 1.44e9 (threshold 3.24e9) twice, bit-identical. Do NOT keep
// wker/depthwise in f64 (r4: 7x worse). Do NOT cap VGPRs via launch_bounds
// min-waves (r2: 57 GB spill). Do NOT hold 81-element register caches in the
// FC (r5: VGPR 256 + 580 KB/block scratch spill, 5x slowdown) — chunk at 27.
#define RP32S 36          // zero-padded 32x36 state for conv1 (16B-aligned rows)
#define RP40S 44          // (-1)-padded 40x44 state for depthwise (16B-aligned rows)
#define H1_G  (31*33*2)   // h1 ic-pair plane: [31 rows][33 px][2 ic] = 2046 floats
#define H1_ROW (33*2)

struct SharedBufs {
    float rp32[32*RP32S];   //  4608 B
    float rp40[40*RP40S];   //  7040 B
    float h1[4*H1_G];       // 32736 B  [g][y][x][2] ic-pair interleaved
    float pbuf[1296];       //  5184 B  (pooled feats; reused as new-r tmp[784])
    float wker[169];        //   676 B
    float num_s[10];        //    40 B
    float w1s[200];         //   800 B
    float w2i[3200];        // 12800 B  interleaved [oc][g][k][2]
    float b1s[8];
    float b2s[16];
};                          // 63,980 B total

// ---- wave-cooperative FC: quarter-wave (16 lanes) per output, f64 accum,
// chunked register staging (27 at a time) to cap VGPR pressure.
// WT is [OUT][1344] (transposed, zero-padded) in d_ws. p is LDS pbuf[1296].
// Arithmetic order identical to r2/r5 fc_wave: a = sum_{m=0..80} w*p (seq),
// then xor-butterfly 1,2,4,8; f32 bias add.
template<int OUT>
__device__ __forceinline__ void fc_wave(const float* __restrict__ WT,
                                        const float* __restrict__ bias,
                                        const float* __restrict__ p,
                                        float* __restrict__ dst, int tid)
{
    const int lane = tid & 63;
    const int wv   = tid >> 6;    // 0..3
    const int li   = lane & 15;
    const int qq   = lane >> 4;   // quarter 0..3
    const int NB = (OUT + 15) / 16;
    #pragma unroll 1
    for (int jb = 0; jb < NB; ++jb) {
        const int j = jb*16 + wv*4 + qq;
        if (j < OUT) {
            const float* col = WT + j*1344 + li;
            double a = 0.0;
            #pragma unroll 1
            for (int c0 = 0; c0 < 81; c0 += 27) {
                float prc[27], wcc[27];
                #pragma unroll
                for (int m = 0; m < 27; ++m) prc[m] = p[(c0+m)*16 + li];  // wave-broadcast
                #pragma unroll
                for (int m = 0; m < 27; ++m) wcc[m] = col[(c0+m)*16];
                #pragma unroll
                for (int m = 0; m < 27; ++m)
                    a = fma((double)wcc[m], (double)prc[m], a);
            }
            a += __shfl_xor(a, 1, 64);
            a += __shfl_xor(a, 2, 64);
            a += __shfl_xor(a, 4, 64);
            a += __shfl_xor(a, 8, 64);
            if (li == 0) dst[j] = (float)a + bias[j];
        }
    }
}

// fallback if ws too small for transposed weights: per-output lanes, W [1296][OUT]
template<int OUT>
__device__ __forceinline__ void fc_fb(const float* __restrict__ W,
                                      const float* __restrict__ bias,
                                      const float* __restrict__ p,
                                      float* __restrict__ dst, int tid)
{
    if (tid < OUT) {
        double a = 0.0;
        #pragma unroll 2
        for (int i0 = 0; i0 < 1296; i0 += 4) {
            float4 pv = *(const float4*)&p[i0];
            a = fma((double)pv.x, (double)W[(i0+0)*OUT+tid], a);
            a = fma((double)pv.y, (double)W[(i0+1)*OUT+tid], a);
            a = fma((double)pv.z, (double)W[(i0+2)*OUT+tid], a);
            a = fma((double)pv.w, (double)W[(i0+3)*OUT+tid], a);
        }
        dst[tid] = (float)a + bias[tid];
    }
}

__device__ __forceinline__ void trunk_pass(SharedBufs& sb, int tid)
{
    // ---- conv1 5x5 pad2 + relu -> h1 (ic-pair layout). 224 threads:
    // thread = (g=ic-pair, y, half-row). Writes float2 (both channels of pair).
    if (tid < 224) {
        const int g   = tid & 3;
        const int r   = tid >> 2;          // 0..55
        const int y   = r >> 1;            // 0..27
        const int hi  = r & 1;
        const int xh  = hi ? 14 : 0;
        const int ro  = hi ? 2  : 0;
        const int wb  = hi ? 12 : 0;
        const float bA = sb.b1s[2*g], bB = sb.b1s[2*g+1];
        float acc0[14], acc1[14];
        #pragma unroll
        for (int i = 0; i < 14; ++i) { acc0[i] = bA; acc1[i] = bB; }
        const float* w0 = &sb.w1s[(2*g)*25];
        const float* w1 = &sb.w1s[(2*g+1)*25];
        #pragma unroll
        for (int ky = 0; ky < 5; ++ky) {
            const float4* rr4 = (const float4*)&sb.rp32[(y+ky)*RP32S + wb];
            float rv[20];
            #pragma unroll
            for (int q4 = 0; q4 < 5; ++q4) {
                float4 t4 = rr4[q4];
                rv[q4*4+0]=t4.x; rv[q4*4+1]=t4.y; rv[q4*4+2]=t4.z; rv[q4*4+3]=t4.w;
            }
            #pragma unroll
            for (int kx = 0; kx < 5; ++kx) {
                const float wa = w0[ky*5+kx], wc = w1[ky*5+kx];
                #pragma unroll
                for (int xl = 0; xl < 14; ++xl) {
                    const float v = rv[xl + kx + ro];
                    acc0[xl] = fmaf(wa, v, acc0[xl]);
                    acc1[xl] = fmaf(wc, v, acc1[xl]);
                }
            }
        }
        #pragma unroll
        for (int xl = 0; xl < 14; ++xl) {
            float2 st;
            st.x = fmaxf(acc0[xl], 0.f);
            st.y = fmaxf(acc1[xl], 0.f);
            *(float2*)&sb.h1[g*H1_G + (y+2)*H1_ROW + (xh + xl + 2)*2] = st;
        }
    }
    __syncthreads();

    // ---- conv2 5x5 pad2 + relu + maxpool3 -> pbuf[1296]. 240 threads,
    // 2x3 pooled outputs each; ic-pairs read as float2 (b64).
    if (tid < 240) {
        const int c    = tid / 15;
        const int rem  = tid % 15;
        const int pyg  = rem / 3;
        const int pxg  = rem % 3;
        const int row0 = pyg * 6;
        const int col0 = pxg * 9;
        const float bias = sb.b2s[c];
        float acc[54];
        #pragma unroll
        for (int i = 0; i < 54; ++i) acc[i] = bias;
        #pragma unroll 1
        for (int g = 0; g < 4; ++g) {
            float2 wp[25];
            const float2* wsrc = (const float2*)&sb.w2i[((c*4+g)*25)*2];
            #pragma unroll
            for (int t = 0; t < 25; ++t) wp[t] = wsrc[t];
            #pragma unroll
            for (int yy = 0; yy < 10; ++yy) {
                int rr = row0 + yy; rr = rr > 30 ? 30 : rr;  // clamp: pyg==4 extras discarded
                const float2* hp = (const float2*)&sb.h1[g*H1_G + rr*H1_ROW + col0*2];
                float r0[13], r1[13];
                #pragma unroll
                for (int j = 0; j < 13; ++j) { float2 v = hp[j]; r0[j]=v.x; r1[j]=v.y; }
                #pragma unroll
                for (int t = 0; t < 6; ++t) {
                    const int ky = yy - t;
                    if (ky < 0 || ky > 4) continue;  // static after unroll
                    #pragma unroll
                    for (int kx = 0; kx < 5; ++kx) {
                        const float wa = wp[ky*5+kx].x, wc = wp[ky*5+kx].y;
                        #pragma unroll
                        for (int u = 0; u < 9; ++u)
                            acc[t*9+u] = fmaf(wa, r0[u+kx], fmaf(wc, r1[u+kx], acc[t*9+u]));
                    }
                }
            }
        }
        #pragma unroll
        for (int h = 0; h < 2; ++h) {
            const int py = pyg*2 + h;
            if (py < 9) {
                #pragma unroll
                for (int pxi = 0; pxi < 3; ++pxi) {
                    float m = acc[(h*3)*9 + pxi*3];
                    #pragma unroll
                    for (int dy = 0; dy < 3; ++dy)
                        #pragma unroll
                        for (int dx = 0; dx < 3; ++dx)
                            m = fmaxf(m, acc[(h*3+dy)*9 + pxi*3 + dx]);
                    sb.pbuf[c*81 + py*9 + pxg*3 + pxi] = fmaxf(m, 0.f);
                }
            }
        }
    }
    __syncthreads();
}

__device__ __forceinline__ void depthwise13(SharedBufs& sb, int tid)
{
    if (tid < 196) {
        const int y  = tid / 7;
        const int x0 = (tid % 7) * 4;
        float a0=0.f, a1=0.f, a2=0.f, a3=0.f;
        #pragma unroll 1
        for (int ky = 0; ky < 13; ++ky) {
            const float4* rr = (const float4*)&sb.rp40[(y+ky)*RP40S + x0];
            float rv[16];
            #pragma unroll
            for (int q = 0; q < 4; ++q) {
                float4 t = rr[q];
                rv[q*4+0]=t.x; rv[q*4+1]=t.y; rv[q*4+2]=t.z; rv[q*4+3]=t.w;
            }
            const float* wr = &sb.wker[ky*13];
            #pragma unroll
            for (int kx = 0; kx < 13; ++kx) {
                const float w = wr[kx];
                a0 = fmaf(w, rv[kx+0], a0);
                a1 = fmaf(w, rv[kx+1], a1);
                a2 = fmaf(w, rv[kx+2], a2);
                a3 = fmaf(w, rv[kx+3], a3);
            }
        }
        float* dp = &sb.pbuf[y*28 + x0];
        dp[0]=a0; dp[1]=a1; dp[2]=a2; dp[3]=a3;
    }
}

__device__ __forceinline__ void stage_weights(SharedBufs& sb, int tid,
                                              const float* __restrict__ w1,
                                              const float* __restrict__ w2,
                                              const float* __restrict__ b1,
                                              const float* __restrict__ b2)
{
    for (int i = tid; i < 200; i += 256) sb.w1s[i] = w1[i];
    for (int i = tid; i < 3200; i += 256) {
        int oc = i / 200, r = i % 200, ic = r / 25, k = r % 25;
        sb.w2i[((oc*4 + (ic>>1))*25 + k)*2 + (ic&1)] = w2[i];
    }
    if (tid < 8)  sb.b1s[tid] = b1[tid];
    if (tid < 16) sb.b2s[tid] = b2[tid];
}

template<bool USET>
__global__ __launch_bounds__(256)
void modeld_fused(const float* __restrict__ x,
                  const float* __restrict__ n_w1, const float* __restrict__ n_b1,
                  const float* __restrict__ n_w2, const float* __restrict__ n_b2,
                  const float* __restrict__ n_wl, const float* __restrict__ n_bl,
                  const float* __restrict__ c_w1, const float* __restrict__ c_b1,
                  const float* __restrict__ c_w2, const float* __restrict__ c_b2,
                  const float* __restrict__ c_wl, const float* __restrict__ c_bl,
                  const float* __restrict__ wtc, const float* __restrict__ wtn,
                  float* __restrict__ out)
{
    __shared__ SharedBufs sb;
    const int b   = blockIdx.x;
    const int tid = threadIdx.x;

    for (int i = tid; i < 32*RP32S; i += 256) sb.rp32[i] = 0.f;
    for (int i = tid; i < 40*RP40S; i += 256) sb.rp40[i] = -1.f;
    for (int i = tid; i < 4*H1_G;   i += 256) sb.h1[i]   = 0.f;
    __syncthreads();

    float cur[4] = {0.f, 0.f, 0.f, 0.f};
    #pragma unroll
    for (int q = 0; q < 4; ++q) {
        int i = tid + q*256;
        if (i < 784) {
            float v = x[b*784 + i];
            cur[q] = v;
            int yy = i / 28, xx = i % 28;
            sb.rp32[(yy+2)*RP32S + xx + 2] = v;
            sb.rp40[(yy+6)*RP40S + xx + 6] = v;
        }
    }
    stage_weights(sb, tid, n_w1, n_w2, n_b1, n_b2);
    __syncthreads();

    // ---- n-trunk -> num[0..9] (raw, then f32 tanh)
    trunk_pass(sb, tid);
    if (USET) fc_wave<10>(wtn, n_bl, sb.pbuf, sb.num_s, tid);
    else      fc_fb<10>(n_wl, n_bl, sb.pbuf, sb.num_s, tid);
    __syncthreads();
    if (tid < 10) sb.num_s[tid] = tanhf(sb.num_s[tid]);
    stage_weights(sb, tid, c_w1, c_w2, c_b1, c_b2);   // safe: nobody reads w1s/w2i here
    __syncthreads();

    float o[4];
    {
        const float n0 = sb.num_s[0];
        #pragma unroll
        for (int q = 0; q < 4; ++q) o[q] = n0 * cur[q];
    }

    // ---- 9 iterations
    for (int k = 1; k <= 9; ++k) {
        trunk_pass(sb, tid);
        if (USET) fc_wave<169>(wtc, c_bl, sb.pbuf, sb.wker, tid);
        else      fc_fb<169>(c_wl, c_bl, sb.pbuf, sb.wker, tid);
        __syncthreads();
        if (tid < 169) sb.wker[tid] = tanhf(sb.wker[tid]);   // f32 tanh, f32 storage
        __syncthreads();
        depthwise13(sb, tid);
        __syncthreads();
        const float nk = sb.num_s[k];
        #pragma unroll
        for (int q = 0; q < 4; ++q) {
            int i = tid + q*256;
            if (i < 784) {
                float v = sb.pbuf[i];
                o[q] = fmaf(nk, v, o[q]);
                int yy = i / 28, xx = i % 28;
                sb.rp32[(yy+2)*RP32S + xx + 2] = v;
                sb.rp40[(yy+6)*RP40S + xx + 6] = v;
            }
        }
        __syncthreads();
    }

    #pragma unroll
    for (int q = 0; q < 4; ++q) {
        int i = tid + q*256;
        if (i < 784) out[b*784 + i] = o[q];
    }
}

// Build WT: rows 0..168 = c_wl^T (zero-padded 1296->1344), rows 169..178 = n_wl^T.
__global__ void transpose_wl(const float* __restrict__ c_wl,
                             const float* __restrict__ n_wl,
                             float* __restrict__ wt)
{
    int idx = blockIdx.x*256 + threadIdx.x;
    const int TOT = 179*1344;
    if (idx >= TOT) return;
    int j = idx / 1344, i = idx % 1344;
    float v;
    if (j < 169) v = (i < 1296) ? c_wl[i*169 + j]      : 0.f;
    else         v = (i < 1296) ? n_wl[i*10 + (j-169)] : 0.f;
    wt[idx] = v;
}

extern "C" void kernel_launch(void* const* d_in, const int* in_sizes, int n_in,
                              void* d_out, int out_size, void* d_ws, size_t ws_size,
                              hipStream_t stream)
{
    const float* x    = (const float*)d_in[0];
    const float* n_w1 = (const float*)d_in[1];
    const float* n_b1 = (const float*)d_in[2];
    const float* n_w2 = (const float*)d_in[3];
    const float* n_b2 = (const float*)d_in[4];
    const float* n_wl = (const float*)d_in[5];
    const float* n_bl = (const float*)d_in[6];
    const float* c_w1 = (const float*)d_in[7];
    const float* c_b1 = (const float*)d_in[8];
    const float* c_w2 = (const float*)d_in[9];
    const float* c_b2 = (const float*)d_in[10];
    const float* c_wl = (const float*)d_in[11];
    const float* c_bl = (const float*)d_in[12];
    float* out = (float*)d_out;

    const int B = in_sizes[0] / 784;
    const size_t WT_BYTES = (size_t)179 * 1344 * sizeof(float);  // 962,304

    if (ws_size >= WT_BYTES) {
        float* wt = (float*)d_ws;
        hipLaunchKernelGGL(transpose_wl, dim3((179*1344 + 255)/256), dim3(256), 0, stream,
                           c_wl, n_wl, wt);
        hipLaunchKernelGGL(modeld_fused<true>, dim3(B), dim3(256), 0, stream,
                           x, n_w1, n_b1, n_w2, n_b2, n_wl, n_bl,
                           c_w1, c_b1, c_w2, c_b2, c_wl, c_bl,
                           wt, wt + 169*1344, out);
    } else {
        hipLaunchKernelGGL(modeld_fused<false>, dim3(B), dim3(256), 0, stream,
                           x, n_w1, n_b1, n_w2, n_b2, n_wl, n_bl,
                           c_w1, c_b1, c_w2, c_b2, c_wl, c_bl,
                           (const float*)nullptr, (const float*)nullptr, out);
    }
}